// Round 7
// baseline (65.556 us; speedup 1.0000x reference)
//
#include <hip/hip_runtime.h>

// BS=32, N_IND=8 -> 256 problems; N_STEP=100, ORDER=2 -> 3x3 block-tridiagonal
// normal equations (verified R1-R5 fp64 absmax 0.0; R6 fp32 absmax 0.031).
// R7: same CR(1)+PCR-in-registers+shuffles as R6, but the 6 PCR levels are a
// ROLLED loop (dynamic s) to cut the I-cache footprint ~5x — with one wave/CU
// the serial L1I cold-miss stream is on the critical path. Last level skips
// the C'/B' recompute (unused afterwards).
#define NPROB 256
#define NSTEP 100
#define T1    99

// A: symmetric 3x3 as [a00,a01,a02,a11,a12,a22]; C,B: row-major 3x3.
__device__ __forceinline__ void syminv3(const float A[6], float G[6]) {
    const float k00 = A[3] * A[5] - A[4] * A[4];
    const float k01 = A[2] * A[4] - A[1] * A[5];
    const float k02 = A[1] * A[4] - A[2] * A[3];
    const float det = A[0] * k00 + A[1] * k01 + A[2] * k02;
    const float id  = 1.0f / det;
    G[0] = k00 * id;
    G[1] = k01 * id;
    G[2] = k02 * id;
    G[3] = (A[0] * A[5] - A[2] * A[2]) * id;
    G[4] = (A[2] * A[1] - A[0] * A[4]) * id;
    G[5] = (A[0] * A[3] - A[1] * A[1]) * id;
}

__device__ __forceinline__ void symmul(const float G[6], const float M[9], float R[9]) {
#pragma unroll
    for (int c = 0; c < 3; ++c) {
        R[0 + c] = G[0] * M[c] + G[1] * M[3 + c] + G[2] * M[6 + c];
        R[3 + c] = G[1] * M[c] + G[3] * M[3 + c] + G[4] * M[6 + c];
        R[6 + c] = G[2] * M[c] + G[4] * M[3 + c] + G[5] * M[6 + c];
    }
}

__device__ __forceinline__ void symvec(const float G[6], const float v[3], float r[3]) {
    r[0] = G[0] * v[0] + G[1] * v[1] + G[2] * v[2];
    r[1] = G[1] * v[0] + G[3] * v[1] + G[4] * v[2];
    r[2] = G[2] * v[0] + G[4] * v[1] + G[5] * v[2];
}

// pub[21] = (P = A^-1 C, Q = A^-1 B, z = A^-1 b)
__device__ __forceinline__ void pqz(const float A[6], const float C[9],
                                    const float B[9], const float b[3], float pub[21]) {
    float G[6];
    syminv3(A, G);
    symmul(G, C, pub);       // P -> pub[0..8]
    symmul(G, B, pub + 9);   // Q -> pub[9..17]
    symvec(G, b, pub + 18);  // z -> pub[18..20]
}

// PCR/CR row update with neighbor data SL=(P,Q,z)_{left}, SR=(P,Q,z)_{right}:
//   A' = A - C*Q_l - B*P_r ; b' = b - C*z_l - B*z_r ;
//   if (!last): C' = -C*P_l ; B' = -B*Q_r
__device__ __forceinline__ void upd(float A[6], float C[9], float B[9], float b[3],
                                    const float SL[21], const float SR[21], bool last) {
    const float* Pl = SL;      const float* Ql = SL + 9;  const float* zl = SL + 18;
    const float* Pr = SR;      const float* Qr = SR + 9;  const float* zr = SR + 18;

    const int RI[6] = {0, 0, 0, 1, 1, 2};
    const int CI[6] = {0, 1, 2, 1, 2, 2};
#pragma unroll
    for (int e = 0; e < 6; ++e) {
        const int r = RI[e], c = CI[e];
        A[e] -= C[3 * r] * Ql[c] + C[3 * r + 1] * Ql[3 + c] + C[3 * r + 2] * Ql[6 + c]
              + B[3 * r] * Pr[c] + B[3 * r + 1] * Pr[3 + c] + B[3 * r + 2] * Pr[6 + c];
    }
#pragma unroll
    for (int r = 0; r < 3; ++r)
        b[r] -= C[3 * r] * zl[0] + C[3 * r + 1] * zl[1] + C[3 * r + 2] * zl[2]
              + B[3 * r] * zr[0] + B[3 * r + 1] * zr[1] + B[3 * r + 2] * zr[2];

    if (!last) {
        float nC[9], nB[9];
#pragma unroll
        for (int r = 0; r < 3; ++r)
#pragma unroll
            for (int c = 0; c < 3; ++c) {
                nC[3 * r + c] = -(C[3 * r] * Pl[c] + C[3 * r + 1] * Pl[3 + c] + C[3 * r + 2] * Pl[6 + c]);
                nB[3 * r + c] = -(B[3 * r] * Qr[c] + B[3 * r + 1] * Qr[3 + c] + B[3 * r + 2] * Qr[6 + c]);
            }
#pragma unroll
        for (int k = 0; k < 9; ++k) { C[k] = nC[k]; B[k] = nB[k]; }
    }
}

// Build block-row t of the normal equations (verified R1/R5).
__device__ __forceinline__ void build_row(int t, const float* cb, const float* rb,
                                          const float* sb, const float* ivp,
                                          float A[6], float C[9], float B[9], float b[3]) {
    const float c0 = cb[t * 3 + 0];
    const float c1 = cb[t * 3 + 1];
    const float c2 = cb[t * 3 + 2];
    const float r  = rb[t];
    A[0] = c0 * c0; A[1] = c0 * c1; A[2] = c0 * c2;
    A[3] = c1 * c1; A[4] = c1 * c2; A[5] = c2 * c2;
    b[0] = c0 * r;  b[1] = c1 * r;  b[2] = c2 * r;
#pragma unroll
    for (int k = 0; k < 9; ++k) { C[k] = 0.0f; B[k] = 0.0f; }

    if (t == 0) {
        A[0] += 1.0f; A[3] += 1.0f;
        b[0] += ivp[0];
        b[1] += ivp[1];
    }
    if (t < T1) {  // U(h_t); B = E(h_t)^T
        const float h = sb[t], h2 = h * h;
        A[0] += 2.0f;
        A[1] += h;
        A[2] += 0.5f * h2;
        A[3] += h2 + 3.0f;
        A[4] += 0.5f * h2 * h + 1.5f * h;
        A[5] += 0.25f * h2 * h2 + 1.25f * h2;
        B[0] = -2.0f;      B[1] =  h;        B[2] = -0.5f * h2;
        B[3] = -h;         B[4] = -3.0f;     B[5] =  1.5f * h;
        B[6] = -0.5f * h2; B[7] = -1.5f * h; B[8] =  0.25f * h2;
    }
    if (t > 0) {   // V(h_{t-1}); C = E(h_{t-1})
        const float hm = sb[t - 1], hm2 = hm * hm;
        A[0] += 2.0f;
        A[1] -= hm;
        A[2] += 0.5f * hm2;
        A[3] += hm2 + 3.0f;
        A[4] -= 0.5f * hm2 * hm + 1.5f * hm;
        A[5] += 0.25f * hm2 * hm2 + 1.25f * hm2;
        C[0] = -2.0f;       C[1] = -hm;       C[2] = -0.5f * hm2;
        C[3] =  hm;         C[4] = -3.0f;     C[5] = -1.5f * hm;
        C[6] = -0.5f * hm2; C[7] = 1.5f * hm; C[8] = 0.25f * hm2;
    }
}

__device__ __forceinline__ void shflup21(const float v[21], float o[21], int s) {
#pragma unroll
    for (int k = 0; k < 21; ++k) o[k] = __shfl_up(v[k], s, 64);
}
__device__ __forceinline__ void shfldn21(const float v[21], float o[21], int s) {
#pragma unroll
    for (int k = 0; k < 21; ++k) o[k] = __shfl_down(v[k], s, 64);
}

__global__ __launch_bounds__(64, 1) void ode_pcr_shfl_kernel(
    const float* __restrict__ coeffs,  // [256][100][3]
    const float* __restrict__ rhs,     // [256][100]
    const float* __restrict__ iv_rhs,  // [256][2]
    const float* __restrict__ steps,   // [256][99]
    float* __restrict__ out)           // u0[25600] u1[25600] u2[25600] eps[256] st[25344]
{
    const int b = blockIdx.x;
    const int L = threadIdx.x;
    const bool act = (L < 50);

    const float* cb  = coeffs + b * NSTEP * 3;
    const float* rb  = rhs    + b * NSTEP;
    const float* sb  = steps  + b * T1;
    const float* ivp = iv_rhs + b * 2;

    float Ae[6], Ce[9], Be[9], be[3];  // even row 2L of the 50-row system
    float pubo[21];                    // odd row 2L+1 publish data (kept for recovery)
#pragma unroll
    for (int k = 0; k < 21; ++k) pubo[k] = 0.0f;
#pragma unroll
    for (int k = 0; k < 6; ++k) Ae[k] = 0.0f;
#pragma unroll
    for (int k = 0; k < 9; ++k) { Ce[k] = 0.0f; Be[k] = 0.0f; }
    be[0] = be[1] = be[2] = 0.0f;

    // ---------- build + CR pre-step: fold odd rows into even rows ----------
    if (act) {
        build_row(2 * L, cb, rb, sb, ivp, Ae, Ce, Be, be);
        float Ao[6], Co[9], Bo[9], bo[3];
        build_row(2 * L + 1, cb, rb, sb, ivp, Ao, Co, Bo, bo);
        pqz(Ao, Co, Bo, bo, pubo);
    }
    {
        float SL[21];
        shflup21(pubo, SL, 1);         // lane L-1's odd pub; L==0: self, killed by Ce==0
        if (act) upd(Ae, Ce, Be, be, SL, pubo, false);
    }

    // ---------- 6 PCR levels on the 50-row system (s = 1..32), ROLLED ----------
#pragma unroll 1
    for (int s = 1; s < 64; s <<= 1) {
        float pub[21];
#pragma unroll
        for (int k = 0; k < 21; ++k) pub[k] = 0.0f;
        if (act) pqz(Ae, Ce, Be, be, pub);
        float SL[21], SR[21];
        shflup21(pub, SL, s);          // out-of-range -> self, killed by zero C block
        shfldn21(pub, SR, s);          // out-of-range -> self/zero-lane, killed by zero B
        if (act) upd(Ae, Ce, Be, be, SL, SR, s == 32);
    }

    // ---------- local solve, x-exchange via shfl, odd-row recovery ----------
    float xe[3] = {0.0f, 0.0f, 0.0f};
    if (act) {
        float G[6];
        syminv3(Ae, G);
        symvec(G, be, xe);
    }
    float xr[3];
    xr[0] = __shfl_down(xe[0], 1, 64);
    xr[1] = __shfl_down(xe[1], 1, 64);
    xr[2] = __shfl_down(xe[2], 1, 64);  // L==49 reads lane 50: xe there is 0

    if (act) {
        const float* Po = pubo;
        const float* Qo = pubo + 9;
        const float* zo = pubo + 18;
        float xo[3];
#pragma unroll
        for (int r = 0; r < 3; ++r)
            xo[r] = zo[r]
                  - (Po[3 * r] * xe[0] + Po[3 * r + 1] * xe[1] + Po[3 * r + 2] * xe[2])
                  - (Qo[3 * r] * xr[0] + Qo[3 * r + 1] * xr[1] + Qo[3 * r + 2] * xr[2]);

        const int t0 = 2 * L, t1 = 2 * L + 1;
        out[            b * NSTEP + t0] = xe[0];
        out[            b * NSTEP + t1] = xo[0];
        out[25600 +     b * NSTEP + t0] = xe[1];
        out[25600 +     b * NSTEP + t1] = xo[1];
        out[51200 +     b * NSTEP + t0] = xe[2];
        out[51200 +     b * NSTEP + t1] = xo[2];
    }

    // eps + st copy (d_out is re-poisoned before every launch)
    for (int t = L; t < T1; t += 64)
        out[77056 + b * T1 + t] = sb[t];
    if (L == 0)
        out[76800 + b] = 0.0f;
}

extern "C" void kernel_launch(void* const* d_in, const int* in_sizes, int n_in,
                              void* d_out, int out_size, void* d_ws, size_t ws_size,
                              hipStream_t stream) {
    const float* coeffs = (const float*)d_in[0];
    const float* rhs    = (const float*)d_in[1];
    const float* iv_rhs = (const float*)d_in[2];
    const float* steps  = (const float*)d_in[3];
    float* out = (float*)d_out;

    ode_pcr_shfl_kernel<<<dim3(NPROB), dim3(64), 0, stream>>>(
        coeffs, rhs, iv_rhs, steps, out);
}